// Round 5
// baseline (121.941 us; speedup 1.0000x reference)
//
#include <hip/hip_runtime.h>
#include <hip/hip_bf16.h>

// FlatConv3x3NNUE R5: transposed MFMA pipeline (A=weights, B=activations).
// Activations stay in registers across all 4 layers: layer L's accumulators
// (lane: batch=l15, ch=16t+4g+r) repack in-lane into layer L+1's B-fragments
// because prep's k-slot->channel convention is c(kq,g,j)=32kq+16(j>>2)+4g+(j&3).
// No LDS for activations; LDS only stages W-fragments (3-buffer, counted vmcnt).

#define BATCH 8192
#define CMAXF 0.9921875f
#define NGRP 5
#define PPG 5

// wf: bf16 [25 p][25 q][8 f][64 lane][8 j]  (8KB per phase, contiguous)
#define WF_TOTAL 2560000
#define PART_BYTE_OFF 5120000  // float [5][8192][32]

using bf16x8 = __attribute__((ext_vector_type(8))) short;
using f32x4  = __attribute__((ext_vector_type(4))) float;

__device__ __forceinline__ unsigned short f2bf(float f) {
  union { float f; unsigned u; } v; v.f = f;
  unsigned u = v.u + 0x7fffu + ((v.u >> 16) & 1u);   // RNE
  return (unsigned short)(u >> 16);
}

__device__ __forceinline__ f32x4 mfma16(bf16x8 a, bf16x8 b, f32x4 c) {
  return __builtin_amdgcn_mfma_f32_16x16x32_bf16(a, b, c, 0, 0, 0);
}

__device__ __forceinline__ void gload_lds16(const unsigned short* g, unsigned short* l) {
  __builtin_amdgcn_global_load_lds(
      (const __attribute__((address_space(1))) unsigned int*)g,
      (__attribute__((address_space(3))) unsigned int*)l, 16, 0, 0);
}

// relu + pack f32x4 -> 2 u32 of bf16 pairs (lo=elem0/2, hi=elem1/3)
__device__ __forceinline__ void relu_pack2(f32x4 v, unsigned& lo, unsigned& hi) {
  union { __hip_bfloat162 h; unsigned u; } a_, b_;
  a_.h = __float22bfloat162_rn(make_float2(fmaxf(v[0], 0.f), fmaxf(v[1], 0.f)));
  b_.h = __float22bfloat162_rn(make_float2(fmaxf(v[2], 0.f), fmaxf(v[3], 0.f)));
  lo = a_.u; hi = b_.u;
}

// ---------------- prep: weights -> bf16 [p][q][f][lane][j] ----------------
// L1 (q=5s): slot (g,j) <-> k = g*8+j (18 real, 18=bias, else 0)
// L2/L3/L4:  slot (g,j) <-> c = 32*kq + 16*(j>>2) + 4*g + (j&3)
__global__ __launch_bounds__(256) void prep_kernel(
    const float* __restrict__ W1, const float* __restrict__ b1,
    const float* __restrict__ W2, const float* __restrict__ W3,
    const float* __restrict__ W4, unsigned short* __restrict__ wf)
{
  int e4 = (blockIdx.x * 256 + threadIdx.x) * 4;
  if (e4 >= WF_TOTAL) return;
  const int j0 = e4 & 7;           // 0 or 4
  const int l = (e4 >> 3) & 63;
  const int f = (e4 >> 9) & 7;
  const int pq = e4 >> 12;
  const int p = pq / 25, q = pq - p * 25;
  const int g = l >> 4, l15 = l & 15;
  unsigned short vv[4];
#pragma unroll
  for (int i = 0; i < 4; ++i) {
    int j = j0 + i;
    float val = 0.f;
    if (q < 20) {
      int s = q / 5, rem = q - s * 5;
      if (rem == 0) {              // L1(s)
        int o = f * 16 + l15;
        int kk = g * 8 + j;
        if (kk < 18) {
          int c = (kk >= 9) ? 1 : 0;
          int rr = kk - c * 9;
          int py = rr / 3, px = rr - py * 3;
          int si = s >> 1, sj = s & 1;
          int di = py - si, dj = px - sj;
          if (di >= 0 && di < 2 && dj >= 0 && dj < 2)
            val = W1[((p * 128 + o) * 2 + c) * 4 + di * 2 + dj];
        } else if (kk == 18) {
          val = b1[p * 128 + o];
        }
      } else {                     // L2(s, kq)
        int kq = rem - 1;
        int o = f * 16 + l15;
        int c = kq * 32 + ((j >> 2) << 4) + g * 4 + (j & 3);
        val = W2[((p * 128 + o) * 128 + c) * 4 + s];
      }
    } else if (q < 24) {           // L3(kq)
      int kq = q - 20;
      int o = f * 16 + l15;
      int c = kq * 32 + ((j >> 2) << 4) + g * 4 + (j & 3);
      val = W3[(p * 128 + o) * 128 + c];
    } else {                       // L4: f = nt*4+kq
      int nt = f >> 2, kq = f & 3;
      int o = nt * 16 + l15;
      int c = kq * 32 + ((j >> 2) << 4) + g * 4 + (j & 3);
      val = W4[(p * 32 + o) * 128 + c];
    }
    vv[i] = f2bf(val);
  }
  ushort4 st; st.x = vv[0]; st.y = vv[1]; st.z = vv[2]; st.w = vv[3];
  *(ushort4*)(wf + e4) = st;
}

// ---------------- tower ----------------
#define WAITV4() asm volatile("s_waitcnt vmcnt(4)" ::: "memory")
#define WAITV0() asm volatile("s_waitcnt vmcnt(0)" ::: "memory")
#define BARX()   { __builtin_amdgcn_s_barrier(); asm volatile("" ::: "memory"); }

// B-frag (bf16x8) from 4 packed u32: slots j<->(t'=2kq+(j>>2), r=j&3)
#define BFRAG(pkm, kq) ({                                        \
  union { unsigned u[4]; bf16x8 v; } _bf;                        \
  _bf.u[0] = pkm[2*(kq)][0];   _bf.u[1] = pkm[2*(kq)][1];        \
  _bf.u[2] = pkm[2*(kq)+1][0]; _bf.u[3] = pkm[2*(kq)+1][1];      \
  _bf.v; })

__global__ __launch_bounds__(128, 2) void tower_kernel(
    const float* __restrict__ x,
    const float* __restrict__ b2v, const float* __restrict__ b3v,
    const float* __restrict__ b4v,
    const unsigned short* __restrict__ wf, float* __restrict__ part)
{
  __shared__ __align__(16) unsigned short ldsB[3 * 4096];   // 24KB W staging
  __shared__ __align__(16) unsigned short xs[2][32 * 98];   // per-wave x rows (bf16)

  const int l = threadIdx.x & 63;
  const int wv = threadIdx.x >> 6;
  const int l15 = l & 15;
  const int g = l >> 4;

  int bid = blockIdx.x;
  int lin = (bid & 7) * 80 + (bid >> 3);     // XCD-contiguous (640 = 8*80, bijective)
  int grp = lin / 128;
  int btile = lin - grp * 128;
  const int R0 = btile * 64 + wv * 32;       // this wave's 32 rows

  unsigned short* xsw = xs[wv];
  // fill xs FIRST (so staging loads are the newest vmcnt entries)
  for (int idx = l; idx < 32 * 98; idx += 64)
    xsw[idx] = f2bf(x[(size_t)R0 * 98 + idx]);

  int bufR = 0, bufS = 2;
#define STAGEQ(pn, qn)                                                            \
  {                                                                               \
    unsigned short* dst_ = ldsB + bufS * 4096;                                    \
    const unsigned short* src_ = wf + ((size_t)((pn) * 25 + (qn)) * 8) * 512 + l * 8; \
    _Pragma("unroll")                                                             \
    for (int ff_ = 0; ff_ < 4; ++ff_) {                                           \
      int f_ = wv * 4 + ff_;                                                      \
      gload_lds16(src_ + f_ * 512, dst_ + f_ * 512);                              \
    }                                                                             \
  }
#define ROT() { bufR = (bufR == 2) ? 0 : bufR + 1; bufS = (bufS == 2) ? 0 : bufS + 1; }

  // prologue: stage q0 fully, then q1 (issue order matters for vmcnt counting)
  {
    int p0 = grp * PPG;
    const unsigned short* s0 = wf + ((size_t)(p0 * 25 + 0) * 8) * 512 + l * 8;
    const unsigned short* s1 = wf + ((size_t)(p0 * 25 + 1) * 8) * 512 + l * 8;
#pragma unroll
    for (int ff = 0; ff < 4; ++ff) {
      int f = wv * 4 + ff;
      gload_lds16(s0 + f * 512, ldsB + f * 512);
    }
#pragma unroll
    for (int ff = 0; ff < 4; ++ff) {
      int f = wv * 4 + ff;
      gload_lds16(s1 + f * 512, ldsB + 4096 + f * 512);
    }
  }

  // per-lane K decode for L1 B-fragment
  int kbase[8]; int kmode[8];   // 0: zero, 1: xs, 2: const one (bias)
#pragma unroll
  for (int j = 0; j < 8; ++j) {
    int k = g * 8 + j;
    if (k < 18) {
      int c = (k >= 9) ? 1 : 0;
      int rr = k - c * 9;
      int py = rr / 3, px = rr - (rr / 3) * 3;
      kbase[j] = c * 49 + py * 7 + px;
      kmode[j] = 1;
    } else { kbase[j] = 0; kmode[j] = (k == 18) ? 2 : 0; }
  }

  const f32x4 zf = {0.f, 0.f, 0.f, 0.f};
  f32x4 facc[2][2] = {{zf, zf}, {zf, zf}};   // [m-tile][nt]

  for (int pp = 0; pp < PPG; ++pp) {
    const int p = grp * PPG + pp;
    const int y0 = p / 5;
    const int x0 = p - y0 * 5;
    const int poff = y0 * 7 + x0;

    // L1 B-fragments (both batch tiles) from xs
    bf16x8 a1x[2];
#pragma unroll
    for (int m = 0; m < 2; ++m) {
#pragma unroll
      for (int j = 0; j < 8; ++j) {
        unsigned short v = 0;
        if (kmode[j] == 1) v = xsw[(m * 16 + l15) * 98 + kbase[j] + poff];
        else if (kmode[j] == 2) v = 0x3F80;   // 1.0 bf16
        a1x[m][j] = (short)v;
      }
    }

    // init L2 accumulators with bias2
    f32x4 acc[8][2];
#pragma unroll
    for (int t = 0; t < 8; ++t) {
      f32x4 b2 = *(const f32x4*)(b2v + p * 128 + t * 16 + g * 4);
      acc[t][0] = b2; acc[t][1] = b2;
    }

    unsigned pk[2][8][2];   // [m][t'][b] packed bf16 activations

    for (int s = 0; s < 4; ++s) {
      // ---- phase q=5s : L1(s) -> pk ----
      WAITV4(); BARX();
      STAGEQ(p, 5 * s + 2);
      {
        const unsigned short* bbuf = ldsB + bufR * 4096;
        __builtin_amdgcn_s_setprio(1);
#pragma unroll
        for (int t = 0; t < 8; ++t) {
          bf16x8 bw = *(const bf16x8*)(bbuf + t * 512 + l * 8);
          f32x4 c0 = mfma16(bw, a1x[0], zf);
          f32x4 c1 = mfma16(bw, a1x[1], zf);
          relu_pack2(c0, pk[0][t][0], pk[0][t][1]);
          relu_pack2(c1, pk[1][t][0], pk[1][t][1]);
        }
        __builtin_amdgcn_s_setprio(0);
      }
      ROT();

      // ---- phases q=5s+1+kq : L2(s,kq), acc += W2 . pk ----
#pragma unroll
      for (int kq = 0; kq < 4; ++kq) {
        WAITV4(); BARX();
        STAGEQ(p, 5 * s + 3 + kq);   // q+2 (wraps into L3 q=20,21 at s=3)
        {
          const unsigned short* bbuf = ldsB + bufR * 4096;
          bf16x8 bA = BFRAG(pk[0], kq);
          bf16x8 bB = BFRAG(pk[1], kq);
          __builtin_amdgcn_s_setprio(1);
#pragma unroll
          for (int t = 0; t < 8; ++t) {
            bf16x8 bw = *(const bf16x8*)(bbuf + t * 512 + l * 8);
            acc[t][0] = mfma16(bw, bA, acc[t][0]);
            acc[t][1] = mfma16(bw, bB, acc[t][1]);
          }
          __builtin_amdgcn_s_setprio(0);
        }
        ROT();
      }
    }

    // L2 -> pk ; reinit acc with bias3
#pragma unroll
    for (int t = 0; t < 8; ++t) {
      f32x4 b3 = *(const f32x4*)(b3v + p * 128 + t * 16 + g * 4);
      relu_pack2(acc[t][0], pk[0][t][0], pk[0][t][1]);
      relu_pack2(acc[t][1], pk[1][t][0], pk[1][t][1]);
      acc[t][0] = b3; acc[t][1] = b3;
    }

    // ---- phases q=20..23 : L3(kq) ----
#pragma unroll
    for (int kq = 0; kq < 4; ++kq) {
      WAITV4(); BARX();
      if (kq < 3) { STAGEQ(p, 22 + kq); }
      else if (pp != PPG - 1) { STAGEQ(p + 1, 0); }
      {
        const unsigned short* bbuf = ldsB + bufR * 4096;
        bf16x8 bA = BFRAG(pk[0], kq);
        bf16x8 bB = BFRAG(pk[1], kq);
        __builtin_amdgcn_s_setprio(1);
#pragma unroll
        for (int t = 0; t < 8; ++t) {
          bf16x8 bw = *(const bf16x8*)(bbuf + t * 512 + l * 8);
          acc[t][0] = mfma16(bw, bA, acc[t][0]);
          acc[t][1] = mfma16(bw, bB, acc[t][1]);
        }
        __builtin_amdgcn_s_setprio(0);
      }
      ROT();
    }

    // L3 -> pk
#pragma unroll
    for (int t = 0; t < 8; ++t) {
      relu_pack2(acc[t][0], pk[0][t][0], pk[0][t][1]);
      relu_pack2(acc[t][1], pk[1][t][0], pk[1][t][1]);
    }

    // init L4 accumulators with bias4
    f32x4 c4[2][2];   // [nt][m]
#pragma unroll
    for (int nt = 0; nt < 2; ++nt) {
      f32x4 b4 = *(const f32x4*)(b4v + p * 32 + nt * 16 + g * 4);
      c4[nt][0] = b4; c4[nt][1] = b4;
    }

    // ---- phase q=24 : L4 ----
    if (pp == PPG - 1) { WAITV0(); } else { WAITV4(); }
    BARX();
    if (pp != PPG - 1) { STAGEQ(p + 1, 1); }
    {
      const unsigned short* bbuf = ldsB + bufR * 4096;
      __builtin_amdgcn_s_setprio(1);
#pragma unroll
      for (int kq = 0; kq < 4; ++kq) {
        bf16x8 bA = BFRAG(pk[0], kq);
        bf16x8 bB = BFRAG(pk[1], kq);
#pragma unroll
        for (int nt = 0; nt < 2; ++nt) {
          bf16x8 bw = *(const bf16x8*)(bbuf + (nt * 4 + kq) * 512 + l * 8);
          c4[nt][0] = mfma16(bw, bA, c4[nt][0]);
          c4[nt][1] = mfma16(bw, bB, c4[nt][1]);
        }
      }
      __builtin_amdgcn_s_setprio(0);
      // clamp + accumulate feature partials
#pragma unroll
      for (int nt = 0; nt < 2; ++nt) {
#pragma unroll
        for (int m = 0; m < 2; ++m) {
#pragma unroll
          for (int r = 0; r < 4; ++r) {
            float v = c4[nt][m][r];
            v = fminf(fmaxf(v, -1.f), CMAXF);
            facc[m][nt][r] += v;
          }
        }
      }
    }
    ROT();
  }
#undef STAGEQ
#undef ROT

  // write partials: lane holds (batch=l15 within tile m, ch=nt*16+4g+r)
#pragma unroll
  for (int m = 0; m < 2; ++m) {
#pragma unroll
    for (int nt = 0; nt < 2; ++nt) {
      *(f32x4*)(part + ((size_t)grp * BATCH + R0 + m * 16 + l15) * 32 + nt * 16 + g * 4)
          = facc[m][nt];
    }
  }
}

// ---------------- head: wave-per-2-rows, lane-per-output MLP ----------------
__global__ __launch_bounds__(256) void head_kernel(
    const float* __restrict__ part,
    const float* __restrict__ fc1w, const float* __restrict__ fc1b,
    const float* __restrict__ fc2w, const float* __restrict__ fc2b,
    const float* __restrict__ fc3w, const float* __restrict__ fc3b,
    float* __restrict__ out)
{
  const int lane = threadIdx.x & 63;
  const int o = lane & 31;
  const int half = lane >> 5;
  const int wave = threadIdx.x >> 6;
  const int row = blockIdx.x * 8 + wave * 2 + half;

  float feat = 0.f;
#pragma unroll
  for (int gi = 0; gi < NGRP; ++gi)
    feat += part[((size_t)gi * BATCH + row) * 32 + o];
  feat = feat < 0.f ? 0.f : (feat > CMAXF ? CMAXF : feat);

  float a = fc1b[o];
#pragma unroll
  for (int k = 0; k < 32; ++k)
    a += __shfl(feat, k, 32) * fc1w[o * 32 + k];
  a = a < 0.f ? 0.f : (a > CMAXF ? CMAXF : a);

  float b = fc2b[o];
#pragma unroll
  for (int k = 0; k < 32; ++k)
    b += __shfl(a, k, 32) * fc2w[o * 32 + k];
  b = b < 0.f ? 0.f : (b > CMAXF ? CMAXF : b);

  float c = b * fc3w[o];
#pragma unroll
  for (int m = 16; m >= 1; m >>= 1)
    c += __shfl_xor(c, m, 32);
  if (o == 0) out[row] = c + fc3b[0];
}

extern "C" void kernel_launch(void* const* d_in, const int* in_sizes, int n_in,
                              void* d_out, int out_size, void* d_ws, size_t ws_size,
                              hipStream_t stream) {
  const float* x    = (const float*)d_in[0];
  const float* W1   = (const float*)d_in[1];
  const float* b1   = (const float*)d_in[2];
  const float* W2   = (const float*)d_in[3];
  const float* b2   = (const float*)d_in[4];
  const float* W3   = (const float*)d_in[5];
  const float* b3   = (const float*)d_in[6];
  const float* W4   = (const float*)d_in[7];
  const float* b4   = (const float*)d_in[8];
  const float* fc1w = (const float*)d_in[9];
  const float* fc1b = (const float*)d_in[10];
  const float* fc2w = (const float*)d_in[11];
  const float* fc2b = (const float*)d_in[12];
  const float* fc3w = (const float*)d_in[13];
  const float* fc3b = (const float*)d_in[14];
  float* out = (float*)d_out;

  unsigned short* wf = (unsigned short*)d_ws;
  float* part = (float*)((char*)d_ws + PART_BYTE_OFF);

  prep_kernel<<<WF_TOTAL / 1024, 256, 0, stream>>>(W1, b1, W2, W3, W4, wf);
  tower_kernel<<<640, 128, 0, stream>>>(x, b2, b3, b4, wf, part);
  head_kernel<<<BATCH / 8, 256, 0, stream>>>(part, fc1w, fc1b, fc2w, fc2b, fc3w, fc3b, out);
}

// Round 6
// 86.391 us; speedup vs baseline: 1.4115x; 1.4115x over previous
//
#include <hip/hip_runtime.h>
#include <hip/hip_bf16.h>

// FlatConv3x3NNUE R6: free-running 1-wave blocks; W-fragments global->VGPR with
// explicit wA/wB double-buffer (no LDS staging, no barriers). Activations stay in
// registers across all 4 layers via the R5-verified in-lane repack.

#define BATCH 8192
#define CMAXF 0.9921875f
#define NGRP 5
#define PPG 5

// wf: bf16 [25 p][25 q][8 f][64 lane][8 j]  (8KB per phase, contiguous)
#define WF_TOTAL 2560000
#define PART_BYTE_OFF 5120000  // float [5][8192][32]

using bf16x8 = __attribute__((ext_vector_type(8))) short;
using f32x4  = __attribute__((ext_vector_type(4))) float;

__device__ __forceinline__ unsigned short f2bf(float f) {
  union { float f; unsigned u; } v; v.f = f;
  unsigned u = v.u + 0x7fffu + ((v.u >> 16) & 1u);   // RNE
  return (unsigned short)(u >> 16);
}

__device__ __forceinline__ f32x4 mfma16(bf16x8 a, bf16x8 b, f32x4 c) {
  return __builtin_amdgcn_mfma_f32_16x16x32_bf16(a, b, c, 0, 0, 0);
}

// relu + pack f32x4 -> 2 u32 of bf16 pairs
__device__ __forceinline__ void relu_pack2(f32x4 v, unsigned& lo, unsigned& hi) {
  union { __hip_bfloat162 h; unsigned u; } a_, b_;
  a_.h = __float22bfloat162_rn(make_float2(fmaxf(v[0], 0.f), fmaxf(v[1], 0.f)));
  b_.h = __float22bfloat162_rn(make_float2(fmaxf(v[2], 0.f), fmaxf(v[3], 0.f)));
  lo = a_.u; hi = b_.u;
}

// ---------------- prep: weights -> bf16 [p][q][f][lane][j] (same as R5) ----------------
__global__ __launch_bounds__(256) void prep_kernel(
    const float* __restrict__ W1, const float* __restrict__ b1,
    const float* __restrict__ W2, const float* __restrict__ W3,
    const float* __restrict__ W4, unsigned short* __restrict__ wf)
{
  int e4 = (blockIdx.x * 256 + threadIdx.x) * 4;
  if (e4 >= WF_TOTAL) return;
  const int j0 = e4 & 7;
  const int l = (e4 >> 3) & 63;
  const int f = (e4 >> 9) & 7;
  const int pq = e4 >> 12;
  const int p = pq / 25, q = pq - p * 25;
  const int g = l >> 4, l15 = l & 15;
  unsigned short vv[4];
#pragma unroll
  for (int i = 0; i < 4; ++i) {
    int j = j0 + i;
    float val = 0.f;
    if (q < 20) {
      int s = q / 5, rem = q - s * 5;
      if (rem == 0) {              // L1(s): k = g*8+j (18 real, 18=bias)
        int o = f * 16 + l15;
        int kk = g * 8 + j;
        if (kk < 18) {
          int c = (kk >= 9) ? 1 : 0;
          int rr = kk - c * 9;
          int py = rr / 3, px = rr - py * 3;
          int si = s >> 1, sj = s & 1;
          int di = py - si, dj = px - sj;
          if (di >= 0 && di < 2 && dj >= 0 && dj < 2)
            val = W1[((p * 128 + o) * 2 + c) * 4 + di * 2 + dj];
        } else if (kk == 18) {
          val = b1[p * 128 + o];
        }
      } else {                     // L2(s,kq): c = 32kq + 16(j>>2) + 4g + (j&3)
        int kq = rem - 1;
        int o = f * 16 + l15;
        int c = kq * 32 + ((j >> 2) << 4) + g * 4 + (j & 3);
        val = W2[((p * 128 + o) * 128 + c) * 4 + s];
      }
    } else if (q < 24) {           // L3(kq)
      int kq = q - 20;
      int o = f * 16 + l15;
      int c = kq * 32 + ((j >> 2) << 4) + g * 4 + (j & 3);
      val = W3[(p * 128 + o) * 128 + c];
    } else {                       // L4: f = nt*4+kq
      int nt = f >> 2, kq = f & 3;
      int o = nt * 16 + l15;
      int c = kq * 32 + ((j >> 2) << 4) + g * 4 + (j & 3);
      val = W4[(p * 32 + o) * 128 + c];
    }
    vv[i] = f2bf(val);
  }
  ushort4 st; st.x = vv[0]; st.y = vv[1]; st.z = vv[2]; st.w = vv[3];
  *(ushort4*)(wf + e4) = st;
}

// B-frag (bf16x8) from 4 packed u32
#define BFRAG(pkm, kq) ({                                        \
  union { unsigned u[4]; bf16x8 v; } _bf;                        \
  _bf.u[0] = pkm[2*(kq)][0];   _bf.u[1] = pkm[2*(kq)][1];        \
  _bf.u[2] = pkm[2*(kq)+1][0]; _bf.u[3] = pkm[2*(kq)+1][1];      \
  _bf.v; })

// ---------------- tower: 1 wave/block, reg-direct W, no barriers ----------------
__global__ __launch_bounds__(64, 2) void tower_kernel(
    const float* __restrict__ x,
    const float* __restrict__ b2v, const float* __restrict__ b3v,
    const float* __restrict__ b4v,
    const unsigned short* __restrict__ wf, float* __restrict__ part)
{
  __shared__ __align__(16) unsigned short xsw[32 * 98];

  const int l = threadIdx.x;
  const int l15 = l & 15;
  const int g = l >> 4;

  // XCD-contiguous bijective remap: 1280 = 8 * 160
  int bid = blockIdx.x;
  int lin = (bid & 7) * 160 + (bid >> 3);
  int grp = lin >> 8;          // 0..4
  int btile = lin & 255;       // 0..255
  const int R0 = btile * 32;

  for (int idx = l; idx < 32 * 98; idx += 64)
    xsw[idx] = f2bf(x[(size_t)R0 * 98 + idx]);
  __syncthreads();

  // per-lane K decode for L1 B-fragment
  int kbase[8]; int kmode[8];   // 0: zero, 1: xs, 2: const one (bias)
#pragma unroll
  for (int j = 0; j < 8; ++j) {
    int k = g * 8 + j;
    if (k < 18) {
      int c = (k >= 9) ? 1 : 0;
      int rr = k - c * 9;
      int py = rr / 3, px = rr - (rr / 3) * 3;
      kbase[j] = c * 49 + py * 7 + px;
      kmode[j] = 1;
    } else { kbase[j] = 0; kmode[j] = (k == 18) ? 2 : 0; }
  }

  const f32x4 zf = {0.f, 0.f, 0.f, 0.f};
  f32x4 facc[2][2] = {{zf, zf}, {zf, zf}};   // [m][nt]

  bf16x8 wA[8], wB[8];

#define PRE(DST, PN, QN)                                                          \
  {                                                                               \
    const unsigned short* s_ = wf + ((size_t)((PN) * 25 + (QN)) * 8) * 512 + l * 8; \
    _Pragma("unroll")                                                             \
    for (int f_ = 0; f_ < 8; ++f_) DST[f_] = *(const bf16x8*)(s_ + f_ * 512);     \
  }

#define L1PH(W)                                                                   \
  {                                                                               \
    __builtin_amdgcn_s_setprio(1);                                                \
    _Pragma("unroll")                                                             \
    for (int t_ = 0; t_ < 8; ++t_) {                                              \
      f32x4 c0_ = mfma16(W[t_], a1x[0], zf);                                      \
      f32x4 c1_ = mfma16(W[t_], a1x[1], zf);                                      \
      relu_pack2(c0_, pk[0][t_][0], pk[0][t_][1]);                                \
      relu_pack2(c1_, pk[1][t_][0], pk[1][t_][1]);                                \
    }                                                                             \
    __builtin_amdgcn_s_setprio(0);                                                \
  }

#define L2PH(W, KQ)                                                               \
  {                                                                               \
    bf16x8 bA_ = BFRAG(pk[0], KQ), bB_ = BFRAG(pk[1], KQ);                        \
    __builtin_amdgcn_s_setprio(1);                                                \
    _Pragma("unroll")                                                             \
    for (int t_ = 0; t_ < 8; ++t_) {                                              \
      acc[t_][0] = mfma16(W[t_], bA_, acc[t_][0]);                                \
      acc[t_][1] = mfma16(W[t_], bB_, acc[t_][1]);                                \
    }                                                                             \
    __builtin_amdgcn_s_setprio(0);                                                \
  }

  // prologue: q0 of first position into wA
  PRE(wA, grp * PPG, 0);

#pragma unroll 1
  for (int pp = 0; pp < PPG; ++pp) {
    const int p = grp * PPG + pp;
    const int y0 = p / 5;
    const int x0 = p - y0 * 5;
    const int poff = y0 * 7 + x0;

    // L1 B-fragments (both batch tiles) from xs
    bf16x8 a1x[2];
#pragma unroll
    for (int m = 0; m < 2; ++m) {
#pragma unroll
      for (int j = 0; j < 8; ++j) {
        unsigned short v = 0;
        if (kmode[j] == 1) v = xsw[(m * 16 + l15) * 98 + kbase[j] + poff];
        else if (kmode[j] == 2) v = 0x3F80;   // 1.0 bf16
        a1x[m][j] = (short)v;
      }
    }

    // L2 accumulators init with bias2
    f32x4 acc[8][2];
#pragma unroll
    for (int t = 0; t < 8; ++t) {
      f32x4 b2 = *(const f32x4*)(b2v + p * 128 + t * 16 + g * 4);
      acc[t][0] = b2; acc[t][1] = b2;
    }

    unsigned pk[2][8][2];   // [m][t'][b]

    // phases q=0..19 : 4 x { L1(s), 4 x L2(s,kq) }  (parity: even q computes wA)
#pragma unroll
    for (int s = 0; s < 4; ++s) {
      if ((s & 1) == 0) { PRE(wB, p, 5 * s + 1); L1PH(wA); }
      else              { PRE(wA, p, 5 * s + 1); L1PH(wB); }
#pragma unroll
      for (int kq = 0; kq < 4; ++kq) {
        if (((5 * s + 1 + kq) & 1) == 0) { PRE(wB, p, 5 * s + 2 + kq); L2PH(wA, kq); }
        else                             { PRE(wA, p, 5 * s + 2 + kq); L2PH(wB, kq); }
      }
    }

    // L2 -> pk ; reinit acc with bias3
#pragma unroll
    for (int t = 0; t < 8; ++t) {
      f32x4 b3 = *(const f32x4*)(b3v + p * 128 + t * 16 + g * 4);
      relu_pack2(acc[t][0], pk[0][t][0], pk[0][t][1]);
      relu_pack2(acc[t][1], pk[1][t][0], pk[1][t][1]);
      acc[t][0] = b3; acc[t][1] = b3;
    }

    // phases q=20..23 : L3(kq)  (q even computes wA)
#pragma unroll
    for (int kq = 0; kq < 4; ++kq) {
      if (((20 + kq) & 1) == 0) { PRE(wB, p, 21 + kq); L2PH(wA, kq); }
      else                      { PRE(wA, p, 21 + kq); L2PH(wB, kq); }
    }

    // L3 -> pk
#pragma unroll
    for (int t = 0; t < 8; ++t) {
      relu_pack2(acc[t][0], pk[0][t][0], pk[0][t][1]);
      relu_pack2(acc[t][1], pk[1][t][0], pk[1][t][1]);
    }

    // L4 accumulators init with bias4
    f32x4 c4[2][2];   // [nt][m]
#pragma unroll
    for (int nt = 0; nt < 2; ++nt) {
      f32x4 b4 = *(const f32x4*)(b4v + p * 32 + nt * 16 + g * 4);
      c4[nt][0] = b4; c4[nt][1] = b4;
    }

    // phase q=24 : L4 (even -> wA); prefetch next position's q0 into wB
    PRE(wB, p + 1, 0);   // pp==4 reads harmless in-bounds garbage (never consumed)
    {
      __builtin_amdgcn_s_setprio(1);
#pragma unroll
      for (int kq = 0; kq < 4; ++kq) {
        bf16x8 bA_ = BFRAG(pk[0], kq), bB_ = BFRAG(pk[1], kq);
#pragma unroll
        for (int nt = 0; nt < 2; ++nt) {
          c4[nt][0] = mfma16(wA[nt * 4 + kq], bA_, c4[nt][0]);
          c4[nt][1] = mfma16(wA[nt * 4 + kq], bB_, c4[nt][1]);
        }
      }
      __builtin_amdgcn_s_setprio(0);
#pragma unroll
      for (int nt = 0; nt < 2; ++nt) {
#pragma unroll
        for (int m = 0; m < 2; ++m) {
#pragma unroll
          for (int r = 0; r < 4; ++r) {
            float v = c4[nt][m][r];
            v = fminf(fmaxf(v, -1.f), CMAXF);
            facc[m][nt][r] += v;
          }
        }
      }
    }

    // restore invariant: wA holds next position's q0
#pragma unroll
    for (int f = 0; f < 8; ++f) wA[f] = wB[f];
  }
#undef PRE
#undef L1PH
#undef L2PH

  // partials: lane holds (batch = l15 within m-tile, ch = nt*16 + 4g + r)
#pragma unroll
  for (int m = 0; m < 2; ++m) {
#pragma unroll
    for (int nt = 0; nt < 2; ++nt) {
      *(f32x4*)(part + ((size_t)grp * BATCH + R0 + m * 16 + l15) * 32 + nt * 16 + g * 4)
          = facc[m][nt];
    }
  }
}

// ---------------- head: wave-per-2-rows, lane-per-output MLP ----------------
__global__ __launch_bounds__(256) void head_kernel(
    const float* __restrict__ part,
    const float* __restrict__ fc1w, const float* __restrict__ fc1b,
    const float* __restrict__ fc2w, const float* __restrict__ fc2b,
    const float* __restrict__ fc3w, const float* __restrict__ fc3b,
    float* __restrict__ out)
{
  const int lane = threadIdx.x & 63;
  const int o = lane & 31;
  const int half = lane >> 5;
  const int wave = threadIdx.x >> 6;
  const int row = blockIdx.x * 8 + wave * 2 + half;

  float feat = 0.f;
#pragma unroll
  for (int gi = 0; gi < NGRP; ++gi)
    feat += part[((size_t)gi * BATCH + row) * 32 + o];
  feat = feat < 0.f ? 0.f : (feat > CMAXF ? CMAXF : feat);

  float a = fc1b[o];
#pragma unroll
  for (int k = 0; k < 32; ++k)
    a += __shfl(feat, k, 32) * fc1w[o * 32 + k];
  a = a < 0.f ? 0.f : (a > CMAXF ? CMAXF : a);

  float b = fc2b[o];
#pragma unroll
  for (int k = 0; k < 32; ++k)
    b += __shfl(a, k, 32) * fc2w[o * 32 + k];
  b = b < 0.f ? 0.f : (b > CMAXF ? CMAXF : b);

  float c = b * fc3w[o];
#pragma unroll
  for (int m = 16; m >= 1; m >>= 1)
    c += __shfl_xor(c, m, 32);
  if (o == 0) out[row] = c + fc3b[0];
}

extern "C" void kernel_launch(void* const* d_in, const int* in_sizes, int n_in,
                              void* d_out, int out_size, void* d_ws, size_t ws_size,
                              hipStream_t stream) {
  const float* x    = (const float*)d_in[0];
  const float* W1   = (const float*)d_in[1];
  const float* b1   = (const float*)d_in[2];
  const float* W2   = (const float*)d_in[3];
  const float* b2   = (const float*)d_in[4];
  const float* W3   = (const float*)d_in[5];
  const float* b3   = (const float*)d_in[6];
  const float* W4   = (const float*)d_in[7];
  const float* b4   = (const float*)d_in[8];
  const float* fc1w = (const float*)d_in[9];
  const float* fc1b = (const float*)d_in[10];
  const float* fc2w = (const float*)d_in[11];
  const float* fc2b = (const float*)d_in[12];
  const float* fc3w = (const float*)d_in[13];
  const float* fc3b = (const float*)d_in[14];
  float* out = (float*)d_out;

  unsigned short* wf = (unsigned short*)d_ws;
  float* part = (float*)((char*)d_ws + PART_BYTE_OFF);

  prep_kernel<<<WF_TOTAL / 1024, 256, 0, stream>>>(W1, b1, W2, W3, W4, wf);
  tower_kernel<<<1280, 64, 0, stream>>>(x, b2, b3, b4, wf, part);
  head_kernel<<<BATCH / 8, 256, 0, stream>>>(part, fc1w, fc1b, fc2w, fc2b, fc3w, fc3b, out);
}